// Round 15
// baseline (540.675 us; speedup 1.0000x reference)
//
#include <hip/hip_runtime.h>

#define EPSV 1e-8f
#define BN_EPS 1e-5f
#define LN_2PI 1.8378770664093453f

typedef float v2f __attribute__((ext_vector_type(2)));
__device__ __forceinline__ v2f splat2(float x) { v2f r; r.x = x; r.y = x; return r; }

__device__ __forceinline__ float sigmoidf_(float x) { return 1.0f / (1.0f + expf(-x)); }

// quad_perm DPP lane-xor (VALU pipe, no DS): 0xB1 = xor1 [1,0,3,2], 0x4E = xor2 [2,3,0,1]
template<int C>
__device__ __forceinline__ float dppx(float x) {
    int i = __builtin_amdgcn_mov_dpp(__builtin_bit_cast(int, x), C, 0xF, 0xF, true);
    return __builtin_bit_cast(float, i);
}

// Intermediate layouts: pose = [b][64 pix][256 c], a = [b][64 pix][16 a].
// Conv: FULL-K per block (2 x 128-ic LDS stagings) -> exclusive output slice ->
// plain coalesced stores. Split-K atomics were cross-XCD line ping-pong
// (R13/R14: WRITE ~135 MB regardless of lane coalescing).

// ---------------- conv body: 3x3 pad1 on 8x8, full 256-ic reduction ----------------
template<int NACC>
__device__ __forceinline__ void conv3_body(
    const float* __restrict__ x, const float* __restrict__ w,
    const float* __restrict__ g, const float* __restrict__ b_,
    const float* __restrict__ m, const float* __restrict__ v,
    float* __restrict__ out, int OC,
    int bidx, int ocg, float* xs, int t)
{
    const int pix = t & 63, py = pix >> 3, px = pix & 7;
    const int ocb_u = __builtin_amdgcn_readfirstlane(t >> 6);
    const int OCB = 4 * NACC;

    float acc[NACC];
    #pragma unroll
    for (int q = 0; q < NACC; ++q) acc[q] = 0.f;

    for (int ch = 0; ch < 2; ++ch) {
        const int ic0 = ch * 128;
        if (ch) __syncthreads();           // previous chunk's xs reads complete
        for (int idx = t; idx < 128 * 120; idx += 256) {
            int icl = idx / 120;
            int c = idx - icl * 120;
            int iy = c / 12, ix = c - iy * 12;
            float val = 0.f;
            if (iy >= 1 && iy <= 8 && ix >= 1 && ix <= 8)
                val = x[(bidx * 256 + ic0 + icl) * 64 + (iy - 1) * 8 + (ix - 1)];
            xs[idx] = val;
        }
        __syncthreads();

        const float* wb = w + ((size_t)(ocg * OCB + ocb_u) * 256 + ic0) * 9;
        for (int icl = 0; icl < 128; ++icl) {
            const float* xr = &xs[icl * 120 + py * 12 + px];
            const float* wr = &wb[icl * 9];
            #pragma unroll
            for (int ky = 0; ky < 3; ++ky)
                #pragma unroll
                for (int kx = 0; kx < 3; ++kx) {
                    float xv = xr[ky * 12 + kx];
                    #pragma unroll
                    for (int q = 0; q < NACC; ++q)
                        acc[q] = fmaf(wr[q * 9216 + ky * 3 + kx], xv, acc[q]);
                }
        }
    }
    // ---- epilogue: BN fold, LDS transpose, plain coalesced (oc-fast) stores ----
    __syncthreads();  // xs compute reads done; reuse as transpose buffer [pix][OCB+1]
    #pragma unroll
    for (int q = 0; q < NACC; ++q) {
        int oc = ocg * OCB + ocb_u + 4 * q;
        float sc = g[oc] * rsqrtf(v[oc] + BN_EPS);
        xs[pix * (OCB + 1) + ocb_u + 4 * q] = fmaf(acc[q], sc, b_[oc] - m[oc] * sc);
    }
    __syncthreads();
    const int per = (64 * OCB) / 256;
    #pragma unroll
    for (int e = 0; e < per; ++e) {
        int idx = e * 256 + t;            // lane-consecutive -> consecutive oc
        int pp = idx / OCB, ocl = idx - pp * OCB;
        out[(bidx * 64 + pp) * OC + ocg * OCB + ocl] = xs[pp * (OCB + 1) + ocl];
    }
}

// fused launch: blocks [0,256) = conv_pose (NACC=8, 32b x 8 ocg), [256,288) = conv_a
__global__ __launch_bounds__(256, 4) void k_conv_fused(
    const float* __restrict__ x,
    const float* __restrict__ wa, const float* __restrict__ ga, const float* __restrict__ bba,
    const float* __restrict__ ma, const float* __restrict__ va, float* __restrict__ outa,
    const float* __restrict__ wp, const float* __restrict__ gp, const float* __restrict__ bbp,
    const float* __restrict__ mp, const float* __restrict__ vp, float* __restrict__ outp)
{
    __shared__ float xs[128 * 120];
    const int t = threadIdx.x;
    const int bid = blockIdx.x;
    if (bid < 256) {
        int bidx = bid >> 3, ocg = bid & 7;
        conv3_body<8>(x, wp, gp, bbp, mp, vp, outp, 256, bidx, ocg, xs, t);
    } else {
        int bidx = bid - 256;
        conv3_body<4>(x, wa, ga, bba, ma, va, outa, 16, bidx, 0, xs, t);
    }
}

// ---------------- EM routing, conv-type (k=3, pad=1), A=B=16, P=16 ----------------
// block 768; lane = o*4 + kgl. Packed-fp32 (v2f); DPP quad reduce; float4 partial
// stores; stage-2 on 4 waves. sig_flag applies sigmoid to a_in during staging (em0).
// NOTE: plain __launch_bounds__(768) — a min-waves arg makes the allocator target
// 40 VGPRs and spill the vote array (R9/R10: WRITE 155 MB).
__global__ __launch_bounds__(768) void k_em_conv(
    const float* __restrict__ a_in, const float* __restrict__ pose_in,
    const float* __restrict__ W, const float* __restrict__ bu, const float* __restrict__ ba,
    const float* __restrict__ bng, const float* __restrict__ bnb,
    const float* __restrict__ bnm, const float* __restrict__ bnv,
    float* __restrict__ a_out_g, float* __restrict__ pose_out, int sig_flag)
{
    __shared__ float4 red4[192 * 9] __attribute__((aligned(16)));
    __shared__ float prsum[192];
    __shared__ float a_s[160];
    __shared__ float mu_s[16 * 18], is_s[16 * 18];
    __shared__ float cst0_s[16], aout_s[16], laout_s[16];

    const int t = threadIdx.x;
    const int bidx = blockIdx.x >> 6;
    const int l = blockIdx.x & 63;
    const int y = l >> 3, xo = l & 7;
    const int kgl = t & 3;
    const int o = (t >> 2) & 15;
    const int w_id = t >> 6;
    const int kg = w_id * 4 + kgl;

    float* pc_s = reinterpret_cast<float*>(red4);

    for (int idx = t; idx < 2304; idx += 768) {
        int kk = idx >> 8, c = idx & 255;
        int k = idx >> 4, p = idx & 15;
        int iy = y + kk / 3 - 1, ix = xo + (kk % 3) - 1;
        float val = 0.f;
        if (iy >= 0 && iy < 8 && ix >= 0 && ix < 8)
            val = pose_in[((bidx * 64 + iy * 8 + ix) << 8) + c];
        pc_s[k * 20 + p] = val;
    }
    if (t < 144) {
        int kk = t >> 4;
        int iy = y + kk / 3 - 1, ix = xo + (kk % 3) - 1;
        float raw = (iy >= 0 && iy < 8 && ix >= 0 && ix < 8)
                    ? a_in[((bidx * 64 + iy * 8 + ix) << 4) + (t & 15)] : 0.f;
        a_s[t] = sig_flag ? sigmoidf_(raw) : raw;
    }
    __syncthreads();

    v2f v2[3][8];
    const float4* W4 = reinterpret_cast<const float4*>(W);
    #pragma unroll
    for (int s = 0; s < 3; ++s) {
        int k = kg + 48 * s;
        float pcl[16];
        #pragma unroll
        for (int c = 0; c < 4; ++c) {
            float4 p4 = *reinterpret_cast<const float4*>(&pc_s[k * 20 + c * 4]);
            pcl[c * 4 + 0] = p4.x; pcl[c * 4 + 1] = p4.y; pcl[c * 4 + 2] = p4.z; pcl[c * 4 + 3] = p4.w;
        }
        #pragma unroll
        for (int j = 0; j < 8; ++j) v2[s][j] = splat2(0.f);
        #pragma unroll
        for (int h = 0; h < 4; ++h) {
            float4 wr = W4[(k * 16 + o) * 4 + h];
            v2f wa; wa.x = wr.x; wa.y = wr.y;
            v2f wb; wb.x = wr.z; wb.y = wr.w;
            #pragma unroll
            for (int i = 0; i < 4; ++i) {
                v2f a2 = splat2(pcl[i * 4 + h]);
                v2[s][i * 2]     += a2 * wa;
                v2[s][i * 2 + 1] += a2 * wb;
            }
        }
    }
    float afac[3];
    #pragma unroll
    for (int s = 0; s < 3; ++s) { float av = a_s[kg + 48 * s]; afac[s] = av / (av + EPSV); }
    __syncthreads();

    float lg[3] = {0.f, 0.f, 0.f};
    for (int it = 0; it < 3; ++it) {
        float lam = (it == 0) ? 5.0e-4f : ((it == 1) ? 9.75e-4f : 1.42625e-3f);
        float rw[3];
        if (it == 0) {
            #pragma unroll
            for (int s = 0; s < 3; ++s) rw[s] = 0.0625f * afac[s];
        } else {
            #pragma unroll
            for (int s = 0; s < 3; ++s) {
                float mx = lg[s];
                #pragma unroll
                for (int mk = 4; mk <= 32; mk <<= 1) mx = fmaxf(mx, __shfl_xor(mx, mk, 64));
                float e = expf(lg[s] - mx);
                float den = e;
                #pragma unroll
                for (int mk = 4; mk <= 32; mk <<= 1) den += __shfl_xor(den, mk, 64);
                rw[s] = (e / den) * afac[s];
            }
        }
        float prw = rw[0] + rw[1] + rw[2];
        prw += dppx<0xB1>(prw); prw += dppx<0x4E>(prw);
        if (kgl == 0) prsum[w_id * 16 + o] = prw;
        const int row4 = (w_id * 16 + o) * 9;
        const v2f r0 = splat2(rw[0]), r1 = splat2(rw[1]), r2 = splat2(rw[2]);
        #pragma unroll
        for (int j = 0; j < 8; ++j) {
            v2f a0 = v2[0][j], a1 = v2[1][j], a2 = v2[2][j];
            v2f pm = r0 * a0 + r1 * a1 + r2 * a2;
            v2f pq = r0 * (a0 * a0) + r1 * (a1 * a1) + r2 * (a2 * a2);
            float pmx = pm.x, pmy = pm.y, pqx = pq.x, pqy = pq.y;
            pmx += dppx<0xB1>(pmx); pmx += dppx<0x4E>(pmx);
            pmy += dppx<0xB1>(pmy); pmy += dppx<0x4E>(pmy);
            pqx += dppx<0xB1>(pqx); pqx += dppx<0x4E>(pqx);
            pqy += dppx<0xB1>(pqy); pqy += dppx<0x4E>(pqy);
            if (kgl == 0) red4[row4 + j] = make_float4(pmx, pmy, pqx, pqy);
        }
        __syncthreads();
        if (t < 256) {
            int oo = t >> 4, p = t & 15;
            int jj = p >> 1, sel = p & 1;
            const float* rf = reinterpret_cast<const float*>(red4);
            float spm = 0.f, spq = 0.f, srs = 0.f;
            #pragma unroll
            for (int u = 0; u < 12; ++u) {
                int base = ((u * 16 + oo) * 9 + jj) * 4;
                spm += rf[base + sel];
                spq += rf[base + 2 + sel];
                srs += prsum[u * 16 + oo];
            }
            float invr = 1.f / (srs + EPSV);
            float mu = spm * invr;
            float beta = srs * invr;
            float sig = fmaf(-(2.f - beta) * mu, mu, spq * invr) + EPSV;
            float ls = logf(sig);
            mu_s[oo * 18 + p] = mu;
            is_s[oo * 18 + p] = 1.f / sig;
            float sumls = ls;
            #pragma unroll
            for (int mk = 1; mk <= 8; mk <<= 1) sumls += __shfl_xor(sumls, mk, 64);
            if (p == 0) {
                float cost = srs * fmaf(0.5f, sumls, 16.f * bu[oo]);
                float ao = sigmoidf_(lam * (ba[oo] - cost));
                aout_s[oo] = ao; laout_s[oo] = logf(ao);
                cst0_s[oo] = fmaf(-0.5f, sumls, -8.f * LN_2PI);
            }
        }
        __syncthreads();
        if (it < 2) {
            const v2f* mu2 = reinterpret_cast<const v2f*>(&mu_s[o * 18]);
            const v2f* is2 = reinterpret_cast<const v2f*>(&is_s[o * 18]);
            v2f s0 = splat2(0.f), s1 = splat2(0.f), s2 = splat2(0.f);
            #pragma unroll
            for (int j = 0; j < 8; ++j) {
                v2f m2 = mu2[j], iv = is2[j];
                v2f d0 = v2[0][j] - m2; s0 += (d0 * d0) * iv;
                v2f d1 = v2[1][j] - m2; s1 += (d1 * d1) * iv;
                v2f d2 = v2[2][j] - m2; s2 += (d2 * d2) * iv;
            }
            float cb = cst0_s[o] + laout_s[o];
            lg[0] = fmaf(-0.5f, s0.x + s0.y, cb);
            lg[1] = fmaf(-0.5f, s1.x + s1.y, cb);
            lg[2] = fmaf(-0.5f, s2.x + s2.y, cb);
        }
    }
    if (t < 256) {
        float sc = bng[t] * rsqrtf(bnv[t] + BN_EPS);
        float mu = mu_s[(t >> 4) * 18 + (t & 15)];
        pose_out[((bidx * 64 + l) << 8) + t] = (mu - bnm[t]) * sc + bnb[t];
    }
    if (t < 16) a_out_g[((bidx * 64 + l) << 4) + t] = aout_s[t];
}

// ---------------- EM routing, FC-type (k=4, pad=0), A=16, B=10, P=16 ----------------
__global__ __launch_bounds__(640) void k_em_fc(
    const float* __restrict__ a_in, const float* __restrict__ pose_in,
    const float* __restrict__ W, const float* __restrict__ bu, const float* __restrict__ ba,
    float* __restrict__ out)
{
    __shared__ float pcs[5120];
    __shared__ float rws[2816];
    __shared__ float ain_s[256];
    __shared__ float mu_s[10 * 18], is_s[10 * 18];

    const int t = threadIdx.x;
    const int bidx = blockIdx.x / 25;
    const int l = blockIdx.x % 25;
    const int y = l / 5, xo = l % 5;
    const int o = t >> 6;
    const int g = t & 63;

    for (int idx = t; idx < 4096; idx += 640) {
        int kk = idx >> 8, c = idx & 255;
        int k = idx >> 4, p = idx & 15;
        int iy = y + (kk >> 2), ix = xo + (kk & 3);
        pcs[k * 20 + p] = pose_in[((bidx * 64 + iy * 8 + ix) << 8) + c];
    }
    if (t < 256) {
        int kk = t >> 4;
        int iy = y + (kk >> 2), ix = xo + (kk & 3);
        ain_s[t] = a_in[((bidx * 64 + iy * 8 + ix) << 4) + (t & 15)];
    }
    __syncthreads();

    v2f v2[4][8];
    const float4* W4 = reinterpret_cast<const float4*>(W);
    #pragma unroll
    for (int s = 0; s < 4; ++s) {
        int k = g + 64 * s;
        float pcl[16];
        #pragma unroll
        for (int c = 0; c < 4; ++c) {
            float4 p4 = *reinterpret_cast<const float4*>(&pcs[k * 20 + c * 4]);
            pcl[c * 4 + 0] = p4.x; pcl[c * 4 + 1] = p4.y; pcl[c * 4 + 2] = p4.z; pcl[c * 4 + 3] = p4.w;
        }
        #pragma unroll
        for (int j = 0; j < 8; ++j) v2[s][j] = splat2(0.f);
        #pragma unroll
        for (int h = 0; h < 4; ++h) {
            float4 wr = W4[(k * 10 + o) * 4 + h];
            v2f wa; wa.x = wr.x; wa.y = wr.y;
            v2f wb; wb.x = wr.z; wb.y = wr.w;
            #pragma unroll
            for (int i = 0; i < 4; ++i) {
                v2f a2 = splat2(pcl[i * 4 + h]);
                v2[s][i * 2]     += a2 * wa;
                v2[s][i * 2 + 1] += a2 * wb;
            }
        }
    }

    const float bu_o = bu[o], ba_o = ba[o];
    const int myp = (g >> 2) & 15;
    float aout_f = 0.f;

    for (int it = 0; it < 3; ++it) {
        float lam = (it == 0) ? 5.0e-4f : ((it == 1) ? 9.75e-4f : 1.42625e-3f);
        if (t < 256) {
            float av = ain_s[t];
            if (it == 0) {
                float val = 0.1f * av / (av + EPSV);
                #pragma unroll
                for (int oo = 0; oo < 10; ++oo) rws[t * 11 + oo] = val;
            } else {
                float mx = -1e30f;
                #pragma unroll
                for (int oo = 0; oo < 10; ++oo) mx = fmaxf(mx, rws[t * 11 + oo]);
                float den = 0.f;
                #pragma unroll
                for (int oo = 0; oo < 10; ++oo) den += expf(rws[t * 11 + oo] - mx);
                float sc = av / (den * (av + EPSV));
                #pragma unroll
                for (int oo = 0; oo < 10; ++oo) rws[t * 11 + oo] = expf(rws[t * 11 + oo] - mx) * sc;
            }
        }
        __syncthreads();
        float rwl[4]; float rs = 0.f;
        #pragma unroll
        for (int s = 0; s < 4; ++s) { rwl[s] = rws[(g + 64 * s) * 11 + o]; rs += rwl[s]; }
        #pragma unroll
        for (int mk = 1; mk <= 32; mk <<= 1) rs += __shfl_xor(rs, mk, 64);
        const float invr = 1.f / (rs + EPSV);
        const float beta = rs * invr;
        const v2f q0 = splat2(rwl[0]), q1 = splat2(rwl[1]), q2 = splat2(rwl[2]), q3 = splat2(rwl[3]);
        float mu_p;
        {
            float cur[16];
            #pragma unroll
            for (int j = 0; j < 8; ++j) {
                v2f pm = q0 * v2[0][j] + q1 * v2[1][j] + q2 * v2[2][j] + q3 * v2[3][j];
                cur[2 * j] = pm.x; cur[2 * j + 1] = pm.y;
            }
            { const bool hi = (g & 32) != 0;
              #pragma unroll
              for (int i = 0; i < 8; ++i) {
                  float send = hi ? cur[i] : cur[i + 8];
                  float keep = hi ? cur[i + 8] : cur[i];
                  cur[i] = keep + __shfl_xor(send, 32, 64);
              } }
            { const bool hi = (g & 16) != 0;
              #pragma unroll
              for (int i = 0; i < 4; ++i) {
                  float send = hi ? cur[i] : cur[i + 4];
                  float keep = hi ? cur[i + 4] : cur[i];
                  cur[i] = keep + __shfl_xor(send, 16, 64);
              } }
            { const bool hi = (g & 8) != 0;
              #pragma unroll
              for (int i = 0; i < 2; ++i) {
                  float send = hi ? cur[i] : cur[i + 2];
                  float keep = hi ? cur[i + 2] : cur[i];
                  cur[i] = keep + __shfl_xor(send, 8, 64);
              } }
            { const bool hi = (g & 4) != 0;
              float send = hi ? cur[0] : cur[1];
              float keep = hi ? cur[1] : cur[0];
              cur[0] = keep + __shfl_xor(send, 4, 64); }
            float r = cur[0];
            r += __shfl_xor(r, 1, 64);
            r += __shfl_xor(r, 2, 64);
            mu_p = r * invr;
        }
        if ((g & 3) == 0) mu_s[o * 18 + myp] = mu_p;
        float ls;
        {
            float cur[16];
            #pragma unroll
            for (int j = 0; j < 8; ++j) {
                v2f a0 = v2[0][j], a1 = v2[1][j], a2 = v2[2][j], a3 = v2[3][j];
                v2f pq = q0 * (a0 * a0) + q1 * (a1 * a1) + q2 * (a2 * a2) + q3 * (a3 * a3);
                cur[2 * j] = pq.x; cur[2 * j + 1] = pq.y;
            }
            { const bool hi = (g & 32) != 0;
              #pragma unroll
              for (int i = 0; i < 8; ++i) {
                  float send = hi ? cur[i] : cur[i + 8];
                  float keep = hi ? cur[i + 8] : cur[i];
                  cur[i] = keep + __shfl_xor(send, 32, 64);
              } }
            { const bool hi = (g & 16) != 0;
              #pragma unroll
              for (int i = 0; i < 4; ++i) {
                  float send = hi ? cur[i] : cur[i + 4];
                  float keep = hi ? cur[i + 4] : cur[i];
                  cur[i] = keep + __shfl_xor(send, 16, 64);
              } }
            { const bool hi = (g & 8) != 0;
              #pragma unroll
              for (int i = 0; i < 2; ++i) {
                  float send = hi ? cur[i] : cur[i + 2];
                  float keep = hi ? cur[i + 2] : cur[i];
                  cur[i] = keep + __shfl_xor(send, 8, 64);
              } }
            { const bool hi = (g & 4) != 0;
              float send = hi ? cur[0] : cur[1];
              float keep = hi ? cur[1] : cur[0];
              cur[0] = keep + __shfl_xor(send, 4, 64); }
            float r = cur[0];
            r += __shfl_xor(r, 1, 64);
            r += __shfl_xor(r, 2, 64);
            float E2 = r * invr;
            float sig = fmaf(-(2.f - beta) * mu_p, mu_p, E2) + EPSV;
            ls = logf(sig);
            if ((g & 3) == 0) is_s[o * 18 + myp] = 1.f / sig;
        }
        float sumls = ls;
        #pragma unroll
        for (int mk = 4; mk <= 32; mk <<= 1) sumls += __shfl_xor(sumls, mk, 64);
        float cost = rs * fmaf(0.5f, sumls, 16.f * bu_o);
        float ao = sigmoidf_(lam * (ba_o - cost));
        if (it == 2) aout_f = ao;
        if (it < 2) {
            float cst = fmaf(-0.5f, sumls, -8.f * LN_2PI) + logf(ao);
            const v2f* mu2 = reinterpret_cast<const v2f*>(&mu_s[o * 18]);
            const v2f* is2 = reinterpret_cast<const v2f*>(&is_s[o * 18]);
            v2f s0 = splat2(0.f), s1 = splat2(0.f), s2 = splat2(0.f), s3 = splat2(0.f);
            #pragma unroll
            for (int j = 0; j < 8; ++j) {
                v2f m2 = mu2[j], iv = is2[j];
                v2f d0 = v2[0][j] - m2; s0 += (d0 * d0) * iv;
                v2f d1 = v2[1][j] - m2; s1 += (d1 * d1) * iv;
                v2f d2 = v2[2][j] - m2; s2 += (d2 * d2) * iv;
                v2f d3 = v2[3][j] - m2; s3 += (d3 * d3) * iv;
            }
            rws[(g      ) * 11 + o] = fmaf(-0.5f, s0.x + s0.y, cst);
            rws[(g +  64) * 11 + o] = fmaf(-0.5f, s1.x + s1.y, cst);
            rws[(g + 128) * 11 + o] = fmaf(-0.5f, s2.x + s2.y, cst);
            rws[(g + 192) * 11 + o] = fmaf(-0.5f, s3.x + s3.y, cst);
            __syncthreads();
        }
    }
    if (g == 0) atomicAdd(&out[bidx * 10 + o], aout_f * 0.04f);
}

extern "C" void kernel_launch(void* const* d_in, const int* in_sizes, int n_in,
                              void* d_out, int out_size, void* d_ws, size_t ws_size,
                              hipStream_t stream)
{
    const float* x           = (const float*)d_in[0];
    const float* conv_a_w    = (const float*)d_in[1];
    const float* conv_pose_w = (const float*)d_in[2];
    const float* bn_a_g = (const float*)d_in[3];
    const float* bn_a_b = (const float*)d_in[4];
    const float* bn_a_m = (const float*)d_in[5];
    const float* bn_a_v = (const float*)d_in[6];
    const float* bn_p_g = (const float*)d_in[7];
    const float* bn_p_b = (const float*)d_in[8];
    const float* bn_p_m = (const float*)d_in[9];
    const float* bn_p_v = (const float*)d_in[10];
    const float* em0_W  = (const float*)d_in[11];
    const float* em0_bu = (const float*)d_in[12];
    const float* em0_ba = (const float*)d_in[13];
    const float* bn0_g  = (const float*)d_in[14];
    const float* bn0_b  = (const float*)d_in[15];
    const float* bn0_m  = (const float*)d_in[16];
    const float* bn0_v  = (const float*)d_in[17];
    const float* em1_W  = (const float*)d_in[18];
    const float* em1_bu = (const float*)d_in[19];
    const float* em1_ba = (const float*)d_in[20];
    const float* bn1_g  = (const float*)d_in[21];
    const float* bn1_b  = (const float*)d_in[22];
    const float* bn1_m  = (const float*)d_in[23];
    const float* bn1_v  = (const float*)d_in[24];
    const float* fc_W   = (const float*)d_in[25];
    const float* fc_bu  = (const float*)d_in[26];
    const float* fc_ba  = (const float*)d_in[27];

    float* ws    = (float*)d_ws;
    float* a0    = ws;
    float* pose0 = a0 + 32768;
    float* a1    = pose0 + 524288;
    float* pose1 = a1 + 32768;
    float* a2    = pose1 + 524288;
    float* pose2 = a2 + 32768;
    float* out   = (float*)d_out;

    hipMemsetAsync(d_out, 0, (size_t)out_size * sizeof(float), stream);
    k_conv_fused<<<288, 256, 0, stream>>>(x,
        conv_a_w, bn_a_g, bn_a_b, bn_a_m, bn_a_v, a0,
        conv_pose_w, bn_p_g, bn_p_b, bn_p_m, bn_p_v, pose0);
    k_em_conv<<<2048, 768, 0, stream>>>(a0, pose0, em0_W, em0_bu, em0_ba,
                                        bn0_g, bn0_b, bn0_m, bn0_v, a1, pose1, 1);
    k_em_conv<<<2048, 768, 0, stream>>>(a1, pose1, em1_W, em1_bu, em1_ba,
                                        bn1_g, bn1_b, bn1_m, bn1_v, a2, pose2, 0);
    k_em_fc<<<800, 640, 0, stream>>>(a2, pose2, fc_W, fc_bu, fc_ba, out);
}

// Round 16
// 469.468 us; speedup vs baseline: 1.1517x; 1.1517x over previous
//
#include <hip/hip_runtime.h>

#define EPSV 1e-8f
#define BN_EPS 1e-5f
#define LN_2PI 1.8378770664093453f

typedef float v2f __attribute__((ext_vector_type(2)));
__device__ __forceinline__ v2f splat2(float x) { v2f r; r.x = x; r.y = x; return r; }

__device__ __forceinline__ float sigmoidf_(float x) { return 1.0f / (1.0f + expf(-x)); }

// quad_perm DPP lane-xor (VALU pipe, no DS): 0xB1 = xor1 [1,0,3,2], 0x4E = xor2 [2,3,0,1]
template<int C>
__device__ __forceinline__ float dppx(float x) {
    int i = __builtin_amdgcn_mov_dpp(__builtin_bit_cast(int, x), C, 0xF, 0xF, true);
    return __builtin_bit_cast(float, i);
}

// Intermediate layouts: pose = [b][64 pix][256 c], a = [b][64 pix][16 a].
// Conv: split-K x4 (64-ic LDS chunks, 30.7 KB -> 4 blocks/CU) + coalesced oc-fast
// atomics via LDS transpose. R15's full-K had WRITE 2 MB but only 288 blocks ->
// grid-starved (160 us); R13's 8-way strided atomics ping-ponged 135 MB. This is
// the middle point: 1152 blocks, 4-way coalesced contention.

// ---------------- conv body: 3x3 pad1 on 8x8, 64-ic chunk ----------------
template<int NACC>
__device__ __forceinline__ void conv3_body(
    const float* __restrict__ x, const float* __restrict__ w,
    const float* __restrict__ g, const float* __restrict__ b_,
    const float* __restrict__ m, const float* __restrict__ v,
    float* __restrict__ out, int OC,
    int bidx, int ocg, int icq, float* xs, int t)
{
    const int pix = t & 63, py = pix >> 3, px = pix & 7;
    const int ocb_u = __builtin_amdgcn_readfirstlane(t >> 6);
    const int OCB = 4 * NACC;
    const int ic0 = icq * 64;

    for (int idx = t; idx < 64 * 120; idx += 256) {
        int icl = idx / 120;
        int c = idx - icl * 120;
        int iy = c / 12, ix = c - iy * 12;
        float val = 0.f;
        if (iy >= 1 && iy <= 8 && ix >= 1 && ix <= 8)
            val = x[(bidx * 256 + ic0 + icl) * 64 + (iy - 1) * 8 + (ix - 1)];
        xs[idx] = val;
    }
    __syncthreads();

    float acc[NACC];
    #pragma unroll
    for (int q = 0; q < NACC; ++q) acc[q] = 0.f;

    const float* wb = w + ((size_t)(ocg * OCB + ocb_u) * 256 + ic0) * 9;
    for (int icl = 0; icl < 64; ++icl) {
        const float* xr = &xs[icl * 120 + py * 12 + px];
        const float* wr = &wb[icl * 9];
        #pragma unroll
        for (int ky = 0; ky < 3; ++ky)
            #pragma unroll
            for (int kx = 0; kx < 3; ++kx) {
                float xv = xr[ky * 12 + kx];
                #pragma unroll
                for (int q = 0; q < NACC; ++q)
                    acc[q] = fmaf(wr[q * 9216 + ky * 3 + kx], xv, acc[q]);
            }
    }
    // ---- epilogue: BN fold, LDS transpose, coalesced oc-fast atomics ----
    __syncthreads();  // xs compute reads done; reuse as transpose buffer [pix][OCB+1]
    #pragma unroll
    for (int q = 0; q < NACC; ++q) {
        int oc = ocg * OCB + ocb_u + 4 * q;
        float sc = g[oc] * rsqrtf(v[oc] + BN_EPS);
        float add = acc[q] * sc;
        if (icq == 0) add += b_[oc] - m[oc] * sc;
        xs[pix * (OCB + 1) + ocb_u + 4 * q] = add;
    }
    __syncthreads();
    const int per = (64 * OCB) / 256;
    #pragma unroll
    for (int e = 0; e < per; ++e) {
        int idx = e * 256 + t;            // lane-consecutive -> consecutive oc
        int pp = idx / OCB, ocl = idx - pp * OCB;
        atomicAdd(&out[(bidx * 64 + pp) * OC + ocg * OCB + ocl], xs[pp * (OCB + 1) + ocl]);
    }
}

// fused: blocks [0,1024) = conv_pose (32b x 8 ocg x 4 icq), [1024,1152) = conv_a (32b x 4 icq)
__global__ __launch_bounds__(256, 4) void k_conv_fused(
    const float* __restrict__ x,
    const float* __restrict__ wa, const float* __restrict__ ga, const float* __restrict__ bba,
    const float* __restrict__ ma, const float* __restrict__ va, float* __restrict__ outa,
    const float* __restrict__ wp, const float* __restrict__ gp, const float* __restrict__ bbp,
    const float* __restrict__ mp, const float* __restrict__ vp, float* __restrict__ outp)
{
    __shared__ float xs[64 * 120];
    const int t = threadIdx.x;
    const int bid = blockIdx.x;
    if (bid < 1024) {
        int bidx = bid >> 5, rem = bid & 31;
        int ocg = rem >> 2, icq = rem & 3;
        conv3_body<8>(x, wp, gp, bbp, mp, vp, outp, 256, bidx, ocg, icq, xs, t);
    } else {
        int r = bid - 1024;
        int bidx = r >> 2, icq = r & 3;
        conv3_body<4>(x, wa, ga, bba, ma, va, outa, 16, bidx, 0, icq, xs, t);
    }
}

// ---------------- EM routing, conv-type (k=3, pad=1), A=B=16, P=16 ----------------
// block 768; lane = o*4 + kgl. Packed-fp32 (v2f); DPP quad reduce; float4 partial
// stores; stage-2 on 4 waves. sig_flag applies sigmoid to a_in during staging (em0).
// NOTE: plain __launch_bounds__(768) — a min-waves arg makes the allocator target
// 40 VGPRs and spill the vote array (R9/R10: WRITE 155 MB).
__global__ __launch_bounds__(768) void k_em_conv(
    const float* __restrict__ a_in, const float* __restrict__ pose_in,
    const float* __restrict__ W, const float* __restrict__ bu, const float* __restrict__ ba,
    const float* __restrict__ bng, const float* __restrict__ bnb,
    const float* __restrict__ bnm, const float* __restrict__ bnv,
    float* __restrict__ a_out_g, float* __restrict__ pose_out, int sig_flag)
{
    __shared__ float4 red4[192 * 9] __attribute__((aligned(16)));
    __shared__ float prsum[192];
    __shared__ float a_s[160];
    __shared__ float mu_s[16 * 18], is_s[16 * 18];
    __shared__ float cst0_s[16], aout_s[16], laout_s[16];

    const int t = threadIdx.x;
    const int bidx = blockIdx.x >> 6;
    const int l = blockIdx.x & 63;
    const int y = l >> 3, xo = l & 7;
    const int kgl = t & 3;
    const int o = (t >> 2) & 15;
    const int w_id = t >> 6;
    const int kg = w_id * 4 + kgl;

    float* pc_s = reinterpret_cast<float*>(red4);

    for (int idx = t; idx < 2304; idx += 768) {
        int kk = idx >> 8, c = idx & 255;
        int k = idx >> 4, p = idx & 15;
        int iy = y + kk / 3 - 1, ix = xo + (kk % 3) - 1;
        float val = 0.f;
        if (iy >= 0 && iy < 8 && ix >= 0 && ix < 8)
            val = pose_in[((bidx * 64 + iy * 8 + ix) << 8) + c];
        pc_s[k * 20 + p] = val;
    }
    if (t < 144) {
        int kk = t >> 4;
        int iy = y + kk / 3 - 1, ix = xo + (kk % 3) - 1;
        float raw = (iy >= 0 && iy < 8 && ix >= 0 && ix < 8)
                    ? a_in[((bidx * 64 + iy * 8 + ix) << 4) + (t & 15)] : 0.f;
        a_s[t] = sig_flag ? sigmoidf_(raw) : raw;
    }
    __syncthreads();

    v2f v2[3][8];
    const float4* W4 = reinterpret_cast<const float4*>(W);
    #pragma unroll
    for (int s = 0; s < 3; ++s) {
        int k = kg + 48 * s;
        float pcl[16];
        #pragma unroll
        for (int c = 0; c < 4; ++c) {
            float4 p4 = *reinterpret_cast<const float4*>(&pc_s[k * 20 + c * 4]);
            pcl[c * 4 + 0] = p4.x; pcl[c * 4 + 1] = p4.y; pcl[c * 4 + 2] = p4.z; pcl[c * 4 + 3] = p4.w;
        }
        #pragma unroll
        for (int j = 0; j < 8; ++j) v2[s][j] = splat2(0.f);
        #pragma unroll
        for (int h = 0; h < 4; ++h) {
            float4 wr = W4[(k * 16 + o) * 4 + h];
            v2f wa; wa.x = wr.x; wa.y = wr.y;
            v2f wb; wb.x = wr.z; wb.y = wr.w;
            #pragma unroll
            for (int i = 0; i < 4; ++i) {
                v2f a2 = splat2(pcl[i * 4 + h]);
                v2[s][i * 2]     += a2 * wa;
                v2[s][i * 2 + 1] += a2 * wb;
            }
        }
    }
    float afac[3];
    #pragma unroll
    for (int s = 0; s < 3; ++s) { float av = a_s[kg + 48 * s]; afac[s] = av / (av + EPSV); }
    __syncthreads();

    float lg[3] = {0.f, 0.f, 0.f};
    for (int it = 0; it < 3; ++it) {
        float lam = (it == 0) ? 5.0e-4f : ((it == 1) ? 9.75e-4f : 1.42625e-3f);
        float rw[3];
        if (it == 0) {
            #pragma unroll
            for (int s = 0; s < 3; ++s) rw[s] = 0.0625f * afac[s];
        } else {
            #pragma unroll
            for (int s = 0; s < 3; ++s) {
                float mx = lg[s];
                #pragma unroll
                for (int mk = 4; mk <= 32; mk <<= 1) mx = fmaxf(mx, __shfl_xor(mx, mk, 64));
                float e = expf(lg[s] - mx);
                float den = e;
                #pragma unroll
                for (int mk = 4; mk <= 32; mk <<= 1) den += __shfl_xor(den, mk, 64);
                rw[s] = (e / den) * afac[s];
            }
        }
        float prw = rw[0] + rw[1] + rw[2];
        prw += dppx<0xB1>(prw); prw += dppx<0x4E>(prw);
        if (kgl == 0) prsum[w_id * 16 + o] = prw;
        const int row4 = (w_id * 16 + o) * 9;
        const v2f r0 = splat2(rw[0]), r1 = splat2(rw[1]), r2 = splat2(rw[2]);
        #pragma unroll
        for (int j = 0; j < 8; ++j) {
            v2f a0 = v2[0][j], a1 = v2[1][j], a2 = v2[2][j];
            v2f pm = r0 * a0 + r1 * a1 + r2 * a2;
            v2f pq = r0 * (a0 * a0) + r1 * (a1 * a1) + r2 * (a2 * a2);
            float pmx = pm.x, pmy = pm.y, pqx = pq.x, pqy = pq.y;
            pmx += dppx<0xB1>(pmx); pmx += dppx<0x4E>(pmx);
            pmy += dppx<0xB1>(pmy); pmy += dppx<0x4E>(pmy);
            pqx += dppx<0xB1>(pqx); pqx += dppx<0x4E>(pqx);
            pqy += dppx<0xB1>(pqy); pqy += dppx<0x4E>(pqy);
            if (kgl == 0) red4[row4 + j] = make_float4(pmx, pmy, pqx, pqy);
        }
        __syncthreads();
        if (t < 256) {
            int oo = t >> 4, p = t & 15;
            int jj = p >> 1, sel = p & 1;
            const float* rf = reinterpret_cast<const float*>(red4);
            float spm = 0.f, spq = 0.f, srs = 0.f;
            #pragma unroll
            for (int u = 0; u < 12; ++u) {
                int base = ((u * 16 + oo) * 9 + jj) * 4;
                spm += rf[base + sel];
                spq += rf[base + 2 + sel];
                srs += prsum[u * 16 + oo];
            }
            float invr = 1.f / (srs + EPSV);
            float mu = spm * invr;
            float beta = srs * invr;
            float sig = fmaf(-(2.f - beta) * mu, mu, spq * invr) + EPSV;
            float ls = logf(sig);
            mu_s[oo * 18 + p] = mu;
            is_s[oo * 18 + p] = 1.f / sig;
            float sumls = ls;
            #pragma unroll
            for (int mk = 1; mk <= 8; mk <<= 1) sumls += __shfl_xor(sumls, mk, 64);
            if (p == 0) {
                float cost = srs * fmaf(0.5f, sumls, 16.f * bu[oo]);
                float ao = sigmoidf_(lam * (ba[oo] - cost));
                aout_s[oo] = ao; laout_s[oo] = logf(ao);
                cst0_s[oo] = fmaf(-0.5f, sumls, -8.f * LN_2PI);
            }
        }
        __syncthreads();
        if (it < 2) {
            const v2f* mu2 = reinterpret_cast<const v2f*>(&mu_s[o * 18]);
            const v2f* is2 = reinterpret_cast<const v2f*>(&is_s[o * 18]);
            v2f s0 = splat2(0.f), s1 = splat2(0.f), s2 = splat2(0.f);
            #pragma unroll
            for (int j = 0; j < 8; ++j) {
                v2f m2 = mu2[j], iv = is2[j];
                v2f d0 = v2[0][j] - m2; s0 += (d0 * d0) * iv;
                v2f d1 = v2[1][j] - m2; s1 += (d1 * d1) * iv;
                v2f d2 = v2[2][j] - m2; s2 += (d2 * d2) * iv;
            }
            float cb = cst0_s[o] + laout_s[o];
            lg[0] = fmaf(-0.5f, s0.x + s0.y, cb);
            lg[1] = fmaf(-0.5f, s1.x + s1.y, cb);
            lg[2] = fmaf(-0.5f, s2.x + s2.y, cb);
        }
    }
    if (t < 256) {
        float sc = bng[t] * rsqrtf(bnv[t] + BN_EPS);
        float mu = mu_s[(t >> 4) * 18 + (t & 15)];
        pose_out[((bidx * 64 + l) << 8) + t] = (mu - bnm[t]) * sc + bnb[t];
    }
    if (t < 16) a_out_g[((bidx * 64 + l) << 4) + t] = aout_s[t];
}

// ---------------- EM routing, FC-type (k=4, pad=0), A=16, B=10, P=16 ----------------
__global__ __launch_bounds__(640) void k_em_fc(
    const float* __restrict__ a_in, const float* __restrict__ pose_in,
    const float* __restrict__ W, const float* __restrict__ bu, const float* __restrict__ ba,
    float* __restrict__ out)
{
    __shared__ float pcs[5120];
    __shared__ float rws[2816];
    __shared__ float ain_s[256];
    __shared__ float mu_s[10 * 18], is_s[10 * 18];

    const int t = threadIdx.x;
    const int bidx = blockIdx.x / 25;
    const int l = blockIdx.x % 25;
    const int y = l / 5, xo = l % 5;
    const int o = t >> 6;
    const int g = t & 63;

    for (int idx = t; idx < 4096; idx += 640) {
        int kk = idx >> 8, c = idx & 255;
        int k = idx >> 4, p = idx & 15;
        int iy = y + (kk >> 2), ix = xo + (kk & 3);
        pcs[k * 20 + p] = pose_in[((bidx * 64 + iy * 8 + ix) << 8) + c];
    }
    if (t < 256) {
        int kk = t >> 4;
        int iy = y + (kk >> 2), ix = xo + (kk & 3);
        ain_s[t] = a_in[((bidx * 64 + iy * 8 + ix) << 4) + (t & 15)];
    }
    __syncthreads();

    v2f v2[4][8];
    const float4* W4 = reinterpret_cast<const float4*>(W);
    #pragma unroll
    for (int s = 0; s < 4; ++s) {
        int k = g + 64 * s;
        float pcl[16];
        #pragma unroll
        for (int c = 0; c < 4; ++c) {
            float4 p4 = *reinterpret_cast<const float4*>(&pcs[k * 20 + c * 4]);
            pcl[c * 4 + 0] = p4.x; pcl[c * 4 + 1] = p4.y; pcl[c * 4 + 2] = p4.z; pcl[c * 4 + 3] = p4.w;
        }
        #pragma unroll
        for (int j = 0; j < 8; ++j) v2[s][j] = splat2(0.f);
        #pragma unroll
        for (int h = 0; h < 4; ++h) {
            float4 wr = W4[(k * 10 + o) * 4 + h];
            v2f wa; wa.x = wr.x; wa.y = wr.y;
            v2f wb; wb.x = wr.z; wb.y = wr.w;
            #pragma unroll
            for (int i = 0; i < 4; ++i) {
                v2f a2 = splat2(pcl[i * 4 + h]);
                v2[s][i * 2]     += a2 * wa;
                v2[s][i * 2 + 1] += a2 * wb;
            }
        }
    }

    const float bu_o = bu[o], ba_o = ba[o];
    const int myp = (g >> 2) & 15;
    float aout_f = 0.f;

    for (int it = 0; it < 3; ++it) {
        float lam = (it == 0) ? 5.0e-4f : ((it == 1) ? 9.75e-4f : 1.42625e-3f);
        if (t < 256) {
            float av = ain_s[t];
            if (it == 0) {
                float val = 0.1f * av / (av + EPSV);
                #pragma unroll
                for (int oo = 0; oo < 10; ++oo) rws[t * 11 + oo] = val;
            } else {
                float mx = -1e30f;
                #pragma unroll
                for (int oo = 0; oo < 10; ++oo) mx = fmaxf(mx, rws[t * 11 + oo]);
                float den = 0.f;
                #pragma unroll
                for (int oo = 0; oo < 10; ++oo) den += expf(rws[t * 11 + oo] - mx);
                float sc = av / (den * (av + EPSV));
                #pragma unroll
                for (int oo = 0; oo < 10; ++oo) rws[t * 11 + oo] = expf(rws[t * 11 + oo] - mx) * sc;
            }
        }
        __syncthreads();
        float rwl[4]; float rs = 0.f;
        #pragma unroll
        for (int s = 0; s < 4; ++s) { rwl[s] = rws[(g + 64 * s) * 11 + o]; rs += rwl[s]; }
        #pragma unroll
        for (int mk = 1; mk <= 32; mk <<= 1) rs += __shfl_xor(rs, mk, 64);
        const float invr = 1.f / (rs + EPSV);
        const float beta = rs * invr;
        const v2f q0 = splat2(rwl[0]), q1 = splat2(rwl[1]), q2 = splat2(rwl[2]), q3 = splat2(rwl[3]);
        float mu_p;
        {
            float cur[16];
            #pragma unroll
            for (int j = 0; j < 8; ++j) {
                v2f pm = q0 * v2[0][j] + q1 * v2[1][j] + q2 * v2[2][j] + q3 * v2[3][j];
                cur[2 * j] = pm.x; cur[2 * j + 1] = pm.y;
            }
            { const bool hi = (g & 32) != 0;
              #pragma unroll
              for (int i = 0; i < 8; ++i) {
                  float send = hi ? cur[i] : cur[i + 8];
                  float keep = hi ? cur[i + 8] : cur[i];
                  cur[i] = keep + __shfl_xor(send, 32, 64);
              } }
            { const bool hi = (g & 16) != 0;
              #pragma unroll
              for (int i = 0; i < 4; ++i) {
                  float send = hi ? cur[i] : cur[i + 4];
                  float keep = hi ? cur[i + 4] : cur[i];
                  cur[i] = keep + __shfl_xor(send, 16, 64);
              } }
            { const bool hi = (g & 8) != 0;
              #pragma unroll
              for (int i = 0; i < 2; ++i) {
                  float send = hi ? cur[i] : cur[i + 2];
                  float keep = hi ? cur[i + 2] : cur[i];
                  cur[i] = keep + __shfl_xor(send, 8, 64);
              } }
            { const bool hi = (g & 4) != 0;
              float send = hi ? cur[0] : cur[1];
              float keep = hi ? cur[1] : cur[0];
              cur[0] = keep + __shfl_xor(send, 4, 64); }
            float r = cur[0];
            r += __shfl_xor(r, 1, 64);
            r += __shfl_xor(r, 2, 64);
            mu_p = r * invr;
        }
        if ((g & 3) == 0) mu_s[o * 18 + myp] = mu_p;
        float ls;
        {
            float cur[16];
            #pragma unroll
            for (int j = 0; j < 8; ++j) {
                v2f a0 = v2[0][j], a1 = v2[1][j], a2 = v2[2][j], a3 = v2[3][j];
                v2f pq = q0 * (a0 * a0) + q1 * (a1 * a1) + q2 * (a2 * a2) + q3 * (a3 * a3);
                cur[2 * j] = pq.x; cur[2 * j + 1] = pq.y;
            }
            { const bool hi = (g & 32) != 0;
              #pragma unroll
              for (int i = 0; i < 8; ++i) {
                  float send = hi ? cur[i] : cur[i + 8];
                  float keep = hi ? cur[i + 8] : cur[i];
                  cur[i] = keep + __shfl_xor(send, 32, 64);
              } }
            { const bool hi = (g & 16) != 0;
              #pragma unroll
              for (int i = 0; i < 4; ++i) {
                  float send = hi ? cur[i] : cur[i + 4];
                  float keep = hi ? cur[i + 4] : cur[i];
                  cur[i] = keep + __shfl_xor(send, 16, 64);
              } }
            { const bool hi = (g & 8) != 0;
              #pragma unroll
              for (int i = 0; i < 2; ++i) {
                  float send = hi ? cur[i] : cur[i + 2];
                  float keep = hi ? cur[i + 2] : cur[i];
                  cur[i] = keep + __shfl_xor(send, 8, 64);
              } }
            { const bool hi = (g & 4) != 0;
              float send = hi ? cur[0] : cur[1];
              float keep = hi ? cur[1] : cur[0];
              cur[0] = keep + __shfl_xor(send, 4, 64); }
            float r = cur[0];
            r += __shfl_xor(r, 1, 64);
            r += __shfl_xor(r, 2, 64);
            float E2 = r * invr;
            float sig = fmaf(-(2.f - beta) * mu_p, mu_p, E2) + EPSV;
            ls = logf(sig);
            if ((g & 3) == 0) is_s[o * 18 + myp] = 1.f / sig;
        }
        float sumls = ls;
        #pragma unroll
        for (int mk = 4; mk <= 32; mk <<= 1) sumls += __shfl_xor(sumls, mk, 64);
        float cost = rs * fmaf(0.5f, sumls, 16.f * bu_o);
        float ao = sigmoidf_(lam * (ba_o - cost));
        if (it == 2) aout_f = ao;
        if (it < 2) {
            float cst = fmaf(-0.5f, sumls, -8.f * LN_2PI) + logf(ao);
            const v2f* mu2 = reinterpret_cast<const v2f*>(&mu_s[o * 18]);
            const v2f* is2 = reinterpret_cast<const v2f*>(&is_s[o * 18]);
            v2f s0 = splat2(0.f), s1 = splat2(0.f), s2 = splat2(0.f), s3 = splat2(0.f);
            #pragma unroll
            for (int j = 0; j < 8; ++j) {
                v2f m2 = mu2[j], iv = is2[j];
                v2f d0 = v2[0][j] - m2; s0 += (d0 * d0) * iv;
                v2f d1 = v2[1][j] - m2; s1 += (d1 * d1) * iv;
                v2f d2 = v2[2][j] - m2; s2 += (d2 * d2) * iv;
                v2f d3 = v2[3][j] - m2; s3 += (d3 * d3) * iv;
            }
            rws[(g      ) * 11 + o] = fmaf(-0.5f, s0.x + s0.y, cst);
            rws[(g +  64) * 11 + o] = fmaf(-0.5f, s1.x + s1.y, cst);
            rws[(g + 128) * 11 + o] = fmaf(-0.5f, s2.x + s2.y, cst);
            rws[(g + 192) * 11 + o] = fmaf(-0.5f, s3.x + s3.y, cst);
            __syncthreads();
        }
    }
    if (g == 0) atomicAdd(&out[bidx * 10 + o], aout_f * 0.04f);
}

extern "C" void kernel_launch(void* const* d_in, const int* in_sizes, int n_in,
                              void* d_out, int out_size, void* d_ws, size_t ws_size,
                              hipStream_t stream)
{
    const float* x           = (const float*)d_in[0];
    const float* conv_a_w    = (const float*)d_in[1];
    const float* conv_pose_w = (const float*)d_in[2];
    const float* bn_a_g = (const float*)d_in[3];
    const float* bn_a_b = (const float*)d_in[4];
    const float* bn_a_m = (const float*)d_in[5];
    const float* bn_a_v = (const float*)d_in[6];
    const float* bn_p_g = (const float*)d_in[7];
    const float* bn_p_b = (const float*)d_in[8];
    const float* bn_p_m = (const float*)d_in[9];
    const float* bn_p_v = (const float*)d_in[10];
    const float* em0_W  = (const float*)d_in[11];
    const float* em0_bu = (const float*)d_in[12];
    const float* em0_ba = (const float*)d_in[13];
    const float* bn0_g  = (const float*)d_in[14];
    const float* bn0_b  = (const float*)d_in[15];
    const float* bn0_m  = (const float*)d_in[16];
    const float* bn0_v  = (const float*)d_in[17];
    const float* em1_W  = (const float*)d_in[18];
    const float* em1_bu = (const float*)d_in[19];
    const float* em1_ba = (const float*)d_in[20];
    const float* bn1_g  = (const float*)d_in[21];
    const float* bn1_b  = (const float*)d_in[22];
    const float* bn1_m  = (const float*)d_in[23];
    const float* bn1_v  = (const float*)d_in[24];
    const float* fc_W   = (const float*)d_in[25];
    const float* fc_bu  = (const float*)d_in[26];
    const float* fc_ba  = (const float*)d_in[27];

    float* ws    = (float*)d_ws;
    float* a0    = ws;
    float* pose0 = a0 + 32768;
    float* a1    = pose0 + 524288;
    float* pose1 = a1 + 32768;
    float* a2    = pose1 + 524288;
    float* pose2 = a2 + 32768;
    float* out   = (float*)d_out;

    hipMemsetAsync(d_out, 0, (size_t)out_size * sizeof(float), stream);
    hipMemsetAsync(a0, 0, (size_t)(32768 + 524288) * sizeof(float), stream);
    k_conv_fused<<<1152, 256, 0, stream>>>(x,
        conv_a_w, bn_a_g, bn_a_b, bn_a_m, bn_a_v, a0,
        conv_pose_w, bn_p_g, bn_p_b, bn_p_m, bn_p_v, pose0);
    k_em_conv<<<2048, 768, 0, stream>>>(a0, pose0, em0_W, em0_bu, em0_ba,
                                        bn0_g, bn0_b, bn0_m, bn0_v, a1, pose1, 1);
    k_em_conv<<<2048, 768, 0, stream>>>(a1, pose1, em1_W, em1_bu, em1_ba,
                                        bn1_g, bn1_b, bn1_m, bn1_v, a2, pose2, 0);
    k_em_fc<<<800, 640, 0, stream>>>(a2, pose2, fc_W, fc_bu, fc_ba, out);
}

// Round 17
// 446.400 us; speedup vs baseline: 1.2112x; 1.0517x over previous
//
#include <hip/hip_runtime.h>

#define EPSV 1e-8f
#define BN_EPS 1e-5f
#define LN_2PI 1.8378770664093453f

typedef float v2f __attribute__((ext_vector_type(2)));
__device__ __forceinline__ v2f splat2(float x) { v2f r; r.x = x; r.y = x; return r; }

__device__ __forceinline__ float sigmoidf_(float x) { return 1.0f / (1.0f + expf(-x)); }

// DPP helpers (VALU pipe, no DS): quad_perm 0xB1 = xor1, 0x4E = xor2;
// row_ror:N = 0x120+N rotates within the 16-lane row (closed over stride-N classes).
template<int C>
__device__ __forceinline__ float dppx(float x) {
    int i = __builtin_amdgcn_mov_dpp(__builtin_bit_cast(int, x), C, 0xF, 0xF, true);
    return __builtin_bit_cast(float, i);
}

// Intermediate layouts: pose = [b][64 pix][256 c], a = [b][64 pix][16 a].
// Conv: split-K x4 (64-ic LDS chunks) + coalesced oc-fast atomics via LDS transpose.

// ---------------- conv body: 3x3 pad1 on 8x8, 64-ic chunk ----------------
template<int NACC>
__device__ __forceinline__ void conv3_body(
    const float* __restrict__ x, const float* __restrict__ w,
    const float* __restrict__ g, const float* __restrict__ b_,
    const float* __restrict__ m, const float* __restrict__ v,
    float* __restrict__ out, int OC,
    int bidx, int ocg, int icq, float* xs, int t)
{
    const int pix = t & 63, py = pix >> 3, px = pix & 7;
    const int ocb_u = __builtin_amdgcn_readfirstlane(t >> 6);
    const int OCB = 4 * NACC;
    const int ic0 = icq * 64;

    for (int idx = t; idx < 64 * 120; idx += 256) {
        int icl = idx / 120;
        int c = idx - icl * 120;
        int iy = c / 12, ix = c - iy * 12;
        float val = 0.f;
        if (iy >= 1 && iy <= 8 && ix >= 1 && ix <= 8)
            val = x[(bidx * 256 + ic0 + icl) * 64 + (iy - 1) * 8 + (ix - 1)];
        xs[idx] = val;
    }
    __syncthreads();

    float acc[NACC];
    #pragma unroll
    for (int q = 0; q < NACC; ++q) acc[q] = 0.f;

    const float* wb = w + ((size_t)(ocg * OCB + ocb_u) * 256 + ic0) * 9;
    for (int icl = 0; icl < 64; ++icl) {
        const float* xr = &xs[icl * 120 + py * 12 + px];
        const float* wr = &wb[icl * 9];
        #pragma unroll
        for (int ky = 0; ky < 3; ++ky)
            #pragma unroll
            for (int kx = 0; kx < 3; ++kx) {
                float xv = xr[ky * 12 + kx];
                #pragma unroll
                for (int q = 0; q < NACC; ++q)
                    acc[q] = fmaf(wr[q * 9216 + ky * 3 + kx], xv, acc[q]);
            }
    }
    // ---- epilogue: BN fold, LDS transpose, coalesced oc-fast atomics ----
    __syncthreads();
    #pragma unroll
    for (int q = 0; q < NACC; ++q) {
        int oc = ocg * OCB + ocb_u + 4 * q;
        float sc = g[oc] * rsqrtf(v[oc] + BN_EPS);
        float add = acc[q] * sc;
        if (icq == 0) add += b_[oc] - m[oc] * sc;
        xs[pix * (OCB + 1) + ocb_u + 4 * q] = add;
    }
    __syncthreads();
    const int per = (64 * OCB) / 256;
    #pragma unroll
    for (int e = 0; e < per; ++e) {
        int idx = e * 256 + t;
        int pp = idx / OCB, ocl = idx - pp * OCB;
        atomicAdd(&out[(bidx * 64 + pp) * OC + ocg * OCB + ocl], xs[pp * (OCB + 1) + ocl]);
    }
}

// fused: blocks [0,1024) = conv_pose (32b x 8 ocg x 4 icq), [1024,1152) = conv_a (32b x 4 icq)
__global__ __launch_bounds__(256, 4) void k_conv_fused(
    const float* __restrict__ x,
    const float* __restrict__ wa, const float* __restrict__ ga, const float* __restrict__ bba,
    const float* __restrict__ ma, const float* __restrict__ va, float* __restrict__ outa,
    const float* __restrict__ wp, const float* __restrict__ gp, const float* __restrict__ bbp,
    const float* __restrict__ mp, const float* __restrict__ vp, float* __restrict__ outp)
{
    __shared__ float xs[64 * 120];
    const int t = threadIdx.x;
    const int bid = blockIdx.x;
    if (bid < 1024) {
        int bidx = bid >> 5, rem = bid & 31;
        int ocg = rem >> 2, icq = rem & 3;
        conv3_body<8>(x, wp, gp, bbp, mp, vp, outp, 256, bidx, ocg, icq, xs, t);
    } else {
        int r = bid - 1024;
        int bidx = r >> 2, icq = r & 3;
        conv3_body<4>(x, wa, ga, bba, ma, va, outa, 16, bidx, 0, icq, xs, t);
    }
}

// ---------------- EM routing, conv-type (k=3, pad=1), A=B=16, P=16 ----------------
// block 768; lane = o*4 + kgl. Packed-fp32 (v2f); DPP quad reduce; float4 partial
// stores; stage-2 on 4 waves. In-row reduction levels (strides 4,8 over o; 1..8 over p)
// use DPP row_ror (VALU) instead of shfl (DS) to shorten dependent chains.
// NOTE: plain __launch_bounds__(768) — a min-waves arg spills the vote array.
__global__ __launch_bounds__(768) void k_em_conv(
    const float* __restrict__ a_in, const float* __restrict__ pose_in,
    const float* __restrict__ W, const float* __restrict__ bu, const float* __restrict__ ba,
    const float* __restrict__ bng, const float* __restrict__ bnb,
    const float* __restrict__ bnm, const float* __restrict__ bnv,
    float* __restrict__ a_out_g, float* __restrict__ pose_out, int sig_flag)
{
    __shared__ float4 red4[192 * 9] __attribute__((aligned(16)));
    __shared__ float prsum[192];
    __shared__ float a_s[160];
    __shared__ float mu_s[16 * 18], is_s[16 * 18];
    __shared__ float cst0_s[16], aout_s[16], laout_s[16];

    const int t = threadIdx.x;
    const int bidx = blockIdx.x >> 6;
    const int l = blockIdx.x & 63;
    const int y = l >> 3, xo = l & 7;
    const int kgl = t & 3;
    const int o = (t >> 2) & 15;
    const int w_id = t >> 6;
    const int kg = w_id * 4 + kgl;

    float* pc_s = reinterpret_cast<float*>(red4);

    // staging: float4 per thread, single pass (576 x 16B = 2304 floats), coalesced
    if (t < 576) {
        int kk = t / 64;
        int c4 = (t & 63) << 2;
        int k = (kk << 4) + (c4 >> 4);
        int p = c4 & 15;
        int iy = y + kk / 3 - 1, ix = xo + (kk % 3) - 1;
        float4 val = make_float4(0.f, 0.f, 0.f, 0.f);
        if (iy >= 0 && iy < 8 && ix >= 0 && ix < 8)
            val = *reinterpret_cast<const float4*>(&pose_in[((bidx * 64 + iy * 8 + ix) << 8) + c4]);
        *reinterpret_cast<float4*>(&pc_s[k * 20 + p]) = val;
    }
    if (t < 144) {
        int kk = t >> 4;
        int iy = y + kk / 3 - 1, ix = xo + (kk % 3) - 1;
        float raw = (iy >= 0 && iy < 8 && ix >= 0 && ix < 8)
                    ? a_in[((bidx * 64 + iy * 8 + ix) << 4) + (t & 15)] : 0.f;
        a_s[t] = sig_flag ? sigmoidf_(raw) : raw;
    }
    __syncthreads();

    v2f v2[3][8];
    const float4* W4 = reinterpret_cast<const float4*>(W);
    #pragma unroll
    for (int s = 0; s < 3; ++s) {
        int k = kg + 48 * s;
        float pcl[16];
        #pragma unroll
        for (int c = 0; c < 4; ++c) {
            float4 p4 = *reinterpret_cast<const float4*>(&pc_s[k * 20 + c * 4]);
            pcl[c * 4 + 0] = p4.x; pcl[c * 4 + 1] = p4.y; pcl[c * 4 + 2] = p4.z; pcl[c * 4 + 3] = p4.w;
        }
        #pragma unroll
        for (int j = 0; j < 8; ++j) v2[s][j] = splat2(0.f);
        #pragma unroll
        for (int h = 0; h < 4; ++h) {
            float4 wr = W4[(k * 16 + o) * 4 + h];
            v2f wa; wa.x = wr.x; wa.y = wr.y;
            v2f wb; wb.x = wr.z; wb.y = wr.w;
            #pragma unroll
            for (int i = 0; i < 4; ++i) {
                v2f a2 = splat2(pcl[i * 4 + h]);
                v2[s][i * 2]     += a2 * wa;
                v2[s][i * 2 + 1] += a2 * wb;
            }
        }
    }
    float afac[3];
    #pragma unroll
    for (int s = 0; s < 3; ++s) { float av = a_s[kg + 48 * s]; afac[s] = av / (av + EPSV); }
    __syncthreads();

    float lg[3] = {0.f, 0.f, 0.f};
    for (int it = 0; it < 3; ++it) {
        float lam = (it == 0) ? 5.0e-4f : ((it == 1) ? 9.75e-4f : 1.42625e-3f);
        // ---- softmax over o (strides 4,8 via DPP ror; 16,32 via shfl) ----
        float rw[3];
        if (it == 0) {
            #pragma unroll
            for (int s = 0; s < 3; ++s) rw[s] = 0.0625f * afac[s];
        } else {
            #pragma unroll
            for (int s = 0; s < 3; ++s) {
                float mx = lg[s];
                mx = fmaxf(mx, dppx<0x124>(mx));
                mx = fmaxf(mx, dppx<0x128>(mx));
                mx = fmaxf(mx, __shfl_xor(mx, 16, 64));
                mx = fmaxf(mx, __shfl_xor(mx, 32, 64));
                float e = expf(lg[s] - mx);
                float den = e;
                den += dppx<0x124>(den);
                den += dppx<0x128>(den);
                den += __shfl_xor(den, 16, 64);
                den += __shfl_xor(den, 32, 64);
                rw[s] = (e / den) * afac[s];
            }
        }
        float prw = rw[0] + rw[1] + rw[2];
        prw += dppx<0xB1>(prw); prw += dppx<0x4E>(prw);
        if (kgl == 0) prsum[w_id * 16 + o] = prw;
        const int row4 = (w_id * 16 + o) * 9;
        const v2f r0 = splat2(rw[0]), r1 = splat2(rw[1]), r2 = splat2(rw[2]);
        #pragma unroll
        for (int j = 0; j < 8; ++j) {
            v2f a0 = v2[0][j], a1 = v2[1][j], a2 = v2[2][j];
            v2f pm = r0 * a0 + r1 * a1 + r2 * a2;
            v2f pq = r0 * (a0 * a0) + r1 * (a1 * a1) + r2 * (a2 * a2);
            float pmx = pm.x, pmy = pm.y, pqx = pq.x, pqy = pq.y;
            pmx += dppx<0xB1>(pmx); pmx += dppx<0x4E>(pmx);
            pmy += dppx<0xB1>(pmy); pmy += dppx<0x4E>(pmy);
            pqx += dppx<0xB1>(pqx); pqx += dppx<0x4E>(pqx);
            pqy += dppx<0xB1>(pqy); pqy += dppx<0x4E>(pqy);
            if (kgl == 0) red4[row4 + j] = make_float4(pmx, pmy, pqx, pqy);
        }
        __syncthreads();
        if (t < 256) {
            int oo = t >> 4, p = t & 15;
            int jj = p >> 1, sel = p & 1;
            const float* rf = reinterpret_cast<const float*>(red4);
            float spm = 0.f, spq = 0.f, srs = 0.f;
            #pragma unroll
            for (int u = 0; u < 12; ++u) {
                int base = ((u * 16 + oo) * 9 + jj) * 4;
                spm += rf[base + sel];
                spq += rf[base + 2 + sel];
                srs += prsum[u * 16 + oo];
            }
            float invr = 1.f / (srs + EPSV);
            float mu = spm * invr;
            float beta = srs * invr;
            float sig = fmaf(-(2.f - beta) * mu, mu, spq * invr) + EPSV;
            float ls = logf(sig);
            mu_s[oo * 18 + p] = mu;
            is_s[oo * 18 + p] = 1.f / sig;
            // sum over p (lane bits 0-3): all in-row -> pure DPP ror chain
            float sumls = ls;
            sumls += dppx<0x121>(sumls);
            sumls += dppx<0x122>(sumls);
            sumls += dppx<0x124>(sumls);
            sumls += dppx<0x128>(sumls);
            if (p == 0) {
                float cost = srs * fmaf(0.5f, sumls, 16.f * bu[oo]);
                float ao = sigmoidf_(lam * (ba[oo] - cost));
                aout_s[oo] = ao; laout_s[oo] = logf(ao);
                cst0_s[oo] = fmaf(-0.5f, sumls, -8.f * LN_2PI);
            }
        }
        __syncthreads();
        if (it < 2) {
            const v2f* mu2 = reinterpret_cast<const v2f*>(&mu_s[o * 18]);
            const v2f* is2 = reinterpret_cast<const v2f*>(&is_s[o * 18]);
            v2f s0 = splat2(0.f), s1 = splat2(0.f), s2 = splat2(0.f);
            #pragma unroll
            for (int j = 0; j < 8; ++j) {
                v2f m2 = mu2[j], iv = is2[j];
                v2f d0 = v2[0][j] - m2; s0 += (d0 * d0) * iv;
                v2f d1 = v2[1][j] - m2; s1 += (d1 * d1) * iv;
                v2f d2 = v2[2][j] - m2; s2 += (d2 * d2) * iv;
            }
            float cb = cst0_s[o] + laout_s[o];
            lg[0] = fmaf(-0.5f, s0.x + s0.y, cb);
            lg[1] = fmaf(-0.5f, s1.x + s1.y, cb);
            lg[2] = fmaf(-0.5f, s2.x + s2.y, cb);
        }
    }
    if (t < 256) {
        float sc = bng[t] * rsqrtf(bnv[t] + BN_EPS);
        float mu = mu_s[(t >> 4) * 18 + (t & 15)];
        pose_out[((bidx * 64 + l) << 8) + t] = (mu - bnm[t]) * sc + bnb[t];
    }
    if (t < 16) a_out_g[((bidx * 64 + l) << 4) + t] = aout_s[t];
}

// ---------------- EM routing, FC-type (k=4, pad=0), A=16, B=10, P=16 ----------------
__global__ __launch_bounds__(640) void k_em_fc(
    const float* __restrict__ a_in, const float* __restrict__ pose_in,
    const float* __restrict__ W, const float* __restrict__ bu, const float* __restrict__ ba,
    float* __restrict__ out)
{
    __shared__ float pcs[5120];
    __shared__ float rws[2816];
    __shared__ float ain_s[256];
    __shared__ float mu_s[10 * 18], is_s[10 * 18];

    const int t = threadIdx.x;
    const int bidx = blockIdx.x / 25;
    const int l = blockIdx.x % 25;
    const int y = l / 5, xo = l % 5;
    const int o = t >> 6;
    const int g = t & 63;

    // staging: float4 per element group (1024 x 16B = 4096 floats), 2 passes
    for (int idx = t; idx < 1024; idx += 640) {
        int kk = idx >> 6;
        int c4 = (idx & 63) << 2;
        int k = (kk << 4) + (c4 >> 4);
        int p = c4 & 15;
        int iy = y + (kk >> 2), ix = xo + (kk & 3);
        *reinterpret_cast<float4*>(&pcs[k * 20 + p]) =
            *reinterpret_cast<const float4*>(&pose_in[((bidx * 64 + iy * 8 + ix) << 8) + c4]);
    }
    if (t < 256) {
        int kk = t >> 4;
        int iy = y + (kk >> 2), ix = xo + (kk & 3);
        ain_s[t] = a_in[((bidx * 64 + iy * 8 + ix) << 4) + (t & 15)];
    }
    __syncthreads();

    v2f v2[4][8];
    const float4* W4 = reinterpret_cast<const float4*>(W);
    #pragma unroll
    for (int s = 0; s < 4; ++s) {
        int k = g + 64 * s;
        float pcl[16];
        #pragma unroll
        for (int c = 0; c < 4; ++c) {
            float4 p4 = *reinterpret_cast<const float4*>(&pcs[k * 20 + c * 4]);
            pcl[c * 4 + 0] = p4.x; pcl[c * 4 + 1] = p4.y; pcl[c * 4 + 2] = p4.z; pcl[c * 4 + 3] = p4.w;
        }
        #pragma unroll
        for (int j = 0; j < 8; ++j) v2[s][j] = splat2(0.f);
        #pragma unroll
        for (int h = 0; h < 4; ++h) {
            float4 wr = W4[(k * 10 + o) * 4 + h];
            v2f wa; wa.x = wr.x; wa.y = wr.y;
            v2f wb; wb.x = wr.z; wb.y = wr.w;
            #pragma unroll
            for (int i = 0; i < 4; ++i) {
                v2f a2 = splat2(pcl[i * 4 + h]);
                v2[s][i * 2]     += a2 * wa;
                v2[s][i * 2 + 1] += a2 * wb;
            }
        }
    }

    const float bu_o = bu[o], ba_o = ba[o];
    const int myp = (g >> 2) & 15;
    float aout_f = 0.f;

    for (int it = 0; it < 3; ++it) {
        float lam = (it == 0) ? 5.0e-4f : ((it == 1) ? 9.75e-4f : 1.42625e-3f);
        if (t < 256) {
            float av = ain_s[t];
            if (it == 0) {
                float val = 0.1f * av / (av + EPSV);
                #pragma unroll
                for (int oo = 0; oo < 10; ++oo) rws[t * 11 + oo] = val;
            } else {
                float mx = -1e30f;
                #pragma unroll
                for (int oo = 0; oo < 10; ++oo) mx = fmaxf(mx, rws[t * 11 + oo]);
                float den = 0.f;
                #pragma unroll
                for (int oo = 0; oo < 10; ++oo) den += expf(rws[t * 11 + oo] - mx);
                float sc = av / (den * (av + EPSV));
                #pragma unroll
                for (int oo = 0; oo < 10; ++oo) rws[t * 11 + oo] = expf(rws[t * 11 + oo] - mx) * sc;
            }
        }
        __syncthreads();
        float rwl[4]; float rs = 0.f;
        #pragma unroll
        for (int s = 0; s < 4; ++s) { rwl[s] = rws[(g + 64 * s) * 11 + o]; rs += rwl[s]; }
        rs += dppx<0x121>(rs);
        rs += dppx<0x122>(rs);
        rs += dppx<0x124>(rs);
        rs += dppx<0x128>(rs);
        rs += __shfl_xor(rs, 16, 64);
        rs += __shfl_xor(rs, 32, 64);
        const float invr = 1.f / (rs + EPSV);
        const float beta = rs * invr;
        const v2f q0 = splat2(rwl[0]), q1 = splat2(rwl[1]), q2 = splat2(rwl[2]), q3 = splat2(rwl[3]);
        float mu_p;
        {
            float cur[16];
            #pragma unroll
            for (int j = 0; j < 8; ++j) {
                v2f pm = q0 * v2[0][j] + q1 * v2[1][j] + q2 * v2[2][j] + q3 * v2[3][j];
                cur[2 * j] = pm.x; cur[2 * j + 1] = pm.y;
            }
            { const bool hi = (g & 32) != 0;
              #pragma unroll
              for (int i = 0; i < 8; ++i) {
                  float send = hi ? cur[i] : cur[i + 8];
                  float keep = hi ? cur[i + 8] : cur[i];
                  cur[i] = keep + __shfl_xor(send, 32, 64);
              } }
            { const bool hi = (g & 16) != 0;
              #pragma unroll
              for (int i = 0; i < 4; ++i) {
                  float send = hi ? cur[i] : cur[i + 4];
                  float keep = hi ? cur[i + 4] : cur[i];
                  cur[i] = keep + __shfl_xor(send, 16, 64);
              } }
            { const bool hi = (g & 8) != 0;
              #pragma unroll
              for (int i = 0; i < 2; ++i) {
                  float send = hi ? cur[i] : cur[i + 2];
                  float keep = hi ? cur[i + 2] : cur[i];
                  cur[i] = keep + __shfl_xor(send, 8, 64);
              } }
            { const bool hi = (g & 4) != 0;
              float send = hi ? cur[0] : cur[1];
              float keep = hi ? cur[1] : cur[0];
              cur[0] = keep + __shfl_xor(send, 4, 64); }
            float r = cur[0];
            r += dppx<0xB1>(r);
            r += dppx<0x4E>(r);
            mu_p = r * invr;
        }
        if ((g & 3) == 0) mu_s[o * 18 + myp] = mu_p;
        float ls;
        {
            float cur[16];
            #pragma unroll
            for (int j = 0; j < 8; ++j) {
                v2f a0 = v2[0][j], a1 = v2[1][j], a2 = v2[2][j], a3 = v2[3][j];
                v2f pq = q0 * (a0 * a0) + q1 * (a1 * a1) + q2 * (a2 * a2) + q3 * (a3 * a3);
                cur[2 * j] = pq.x; cur[2 * j + 1] = pq.y;
            }
            { const bool hi = (g & 32) != 0;
              #pragma unroll
              for (int i = 0; i < 8; ++i) {
                  float send = hi ? cur[i] : cur[i + 8];
                  float keep = hi ? cur[i + 8] : cur[i];
                  cur[i] = keep + __shfl_xor(send, 32, 64);
              } }
            { const bool hi = (g & 16) != 0;
              #pragma unroll
              for (int i = 0; i < 4; ++i) {
                  float send = hi ? cur[i] : cur[i + 4];
                  float keep = hi ? cur[i + 4] : cur[i];
                  cur[i] = keep + __shfl_xor(send, 16, 64);
              } }
            { const bool hi = (g & 8) != 0;
              #pragma unroll
              for (int i = 0; i < 2; ++i) {
                  float send = hi ? cur[i] : cur[i + 2];
                  float keep = hi ? cur[i + 2] : cur[i];
                  cur[i] = keep + __shfl_xor(send, 8, 64);
              } }
            { const bool hi = (g & 4) != 0;
              float send = hi ? cur[0] : cur[1];
              float keep = hi ? cur[1] : cur[0];
              cur[0] = keep + __shfl_xor(send, 4, 64); }
            float r = cur[0];
            r += dppx<0xB1>(r);
            r += dppx<0x4E>(r);
            float E2 = r * invr;
            float sig = fmaf(-(2.f - beta) * mu_p, mu_p, E2) + EPSV;
            ls = logf(sig);
            if ((g & 3) == 0) is_s[o * 18 + myp] = 1.f / sig;
        }
        float sumls = ls;
        sumls += dppx<0x124>(sumls);
        sumls += dppx<0x128>(sumls);
        sumls += __shfl_xor(sumls, 16, 64);
        sumls += __shfl_xor(sumls, 32, 64);
        float cost = rs * fmaf(0.5f, sumls, 16.f * bu_o);
        float ao = sigmoidf_(lam * (ba_o - cost));
        if (it == 2) aout_f = ao;
        if (it < 2) {
            float cst = fmaf(-0.5f, sumls, -8.f * LN_2PI) + logf(ao);
            const v2f* mu2 = reinterpret_cast<const v2f*>(&mu_s[o * 18]);
            const v2f* is2 = reinterpret_cast<const v2f*>(&is_s[o * 18]);
            v2f s0 = splat2(0.f), s1 = splat2(0.f), s2 = splat2(0.f), s3 = splat2(0.f);
            #pragma unroll
            for (int j = 0; j < 8; ++j) {
                v2f m2 = mu2[j], iv = is2[j];
                v2f d0 = v2[0][j] - m2; s0 += (d0 * d0) * iv;
                v2f d1 = v2[1][j] - m2; s1 += (d1 * d1) * iv;
                v2f d2 = v2[2][j] - m2; s2 += (d2 * d2) * iv;
                v2f d3 = v2[3][j] - m2; s3 += (d3 * d3) * iv;
            }
            rws[(g      ) * 11 + o] = fmaf(-0.5f, s0.x + s0.y, cst);
            rws[(g +  64) * 11 + o] = fmaf(-0.5f, s1.x + s1.y, cst);
            rws[(g + 128) * 11 + o] = fmaf(-0.5f, s2.x + s2.y, cst);
            rws[(g + 192) * 11 + o] = fmaf(-0.5f, s3.x + s3.y, cst);
            __syncthreads();
        }
    }
    if (g == 0) atomicAdd(&out[bidx * 10 + o], aout_f * 0.04f);
}

extern "C" void kernel_launch(void* const* d_in, const int* in_sizes, int n_in,
                              void* d_out, int out_size, void* d_ws, size_t ws_size,
                              hipStream_t stream)
{
    const float* x           = (const float*)d_in[0];
    const float* conv_a_w    = (const float*)d_in[1];
    const float* conv_pose_w = (const float*)d_in[2];
    const float* bn_a_g = (const float*)d_in[3];
    const float* bn_a_b = (const float*)d_in[4];
    const float* bn_a_m = (const float*)d_in[5];
    const float* bn_a_v = (const float*)d_in[6];
    const float* bn_p_g = (const float*)d_in[7];
    const float* bn_p_b = (const float*)d_in[8];
    const float* bn_p_m = (const float*)d_in[9];
    const float* bn_p_v = (const float*)d_in[10];
    const float* em0_W  = (const float*)d_in[11];
    const float* em0_bu = (const float*)d_in[12];
    const float* em0_ba = (const float*)d_in[13];
    const float* bn0_g  = (const float*)d_in[14];
    const float* bn0_b  = (const float*)d_in[15];
    const float* bn0_m  = (const float*)d_in[16];
    const float* bn0_v  = (const float*)d_in[17];
    const float* em1_W  = (const float*)d_in[18];
    const float* em1_bu = (const float*)d_in[19];
    const float* em1_ba = (const float*)d_in[20];
    const float* bn1_g  = (const float*)d_in[21];
    const float* bn1_b  = (const float*)d_in[22];
    const float* bn1_m  = (const float*)d_in[23];
    const float* bn1_v  = (const float*)d_in[24];
    const float* fc_W   = (const float*)d_in[25];
    const float* fc_bu  = (const float*)d_in[26];
    const float* fc_ba  = (const float*)d_in[27];

    float* ws    = (float*)d_ws;
    float* a0    = ws;
    float* pose0 = a0 + 32768;
    float* a1    = pose0 + 524288;
    float* pose1 = a1 + 32768;
    float* a2    = pose1 + 524288;
    float* pose2 = a2 + 32768;
    float* out   = (float*)d_out;

    hipMemsetAsync(d_out, 0, (size_t)out_size * sizeof(float), stream);
    hipMemsetAsync(a0, 0, (size_t)(32768 + 524288) * sizeof(float), stream);
    k_conv_fused<<<1152, 256, 0, stream>>>(x,
        conv_a_w, bn_a_g, bn_a_b, bn_a_m, bn_a_v, a0,
        conv_pose_w, bn_p_g, bn_p_b, bn_p_m, bn_p_v, pose0);
    k_em_conv<<<2048, 768, 0, stream>>>(a0, pose0, em0_W, em0_bu, em0_ba,
                                        bn0_g, bn0_b, bn0_m, bn0_v, a1, pose1, 1);
    k_em_conv<<<2048, 768, 0, stream>>>(a1, pose1, em1_W, em1_bu, em1_ba,
                                        bn1_g, bn1_b, bn1_m, bn1_v, a2, pose2, 0);
    k_em_fc<<<800, 640, 0, stream>>>(a2, pose2, fc_W, fc_bu, fc_ba, out);
}